// Round 1
// baseline (188.505 us; speedup 1.0000x reference)
//
#include <hip/hip_runtime.h>

#define KPAD 88          // K=85 padded to multiple of 4 (16B-aligned LDS rows)
#define NFEAT 16

// ---------------------------------------------------------------------------
// Kernel 1: per-block partial QF accumulation.
// Block = 256 threads = (f in 0..15) x (j in 0..15). Each block processes
// chunks of 256 points (grid-stride over chunks). Per 16-point batch:
//   phase A: compute E[j][k] = exp(d2(point_j, QX_k) * invw2_k) into LDS
//   phase B: thread (f,j) does acc[k] += E[j][k] * F[point_j][f]  (b128 reads)
// End: reduce acc over j (shfl within wave, LDS across waves) -> partial[block].
// ---------------------------------------------------------------------------
__global__ __launch_bounds__(256) void k1_partial(
    const float* __restrict__ X, const float* __restrict__ F,
    const float* __restrict__ QX, const float* __restrict__ omegaD,
    int K, int chunks, float* __restrict__ partial)
{
    __shared__ float qx0[KPAD], qx1[KPAD], qx2[KPAD], invw2[KPAD];
    __shared__ float E[16][KPAD];            // 16 points x 88 k  (5.6 KB)
    __shared__ float wred[4][KPAD][NFEAT];   // cross-wave reduction (22.5 KB)

    const int tid = threadIdx.x;
    if (tid < KPAD) {
        float a = 0.f, b = 0.f, c = 0.f, iw = 0.f;
        if (tid < K) {
            a = QX[tid * 3 + 0];
            b = QX[tid * 3 + 1];
            c = QX[tid * 3 + 2];
            float w = omegaD[tid];
            iw = 1.0f / (w * w);
        }
        qx0[tid] = a; qx1[tid] = b; qx2[tid] = c; invw2[tid] = iw;
    }

    float acc[KPAD];
#pragma unroll
    for (int k = 0; k < KPAD; ++k) acc[k] = 0.f;

    const int f   = tid & 15;   // feature (phase B) / k-group (phase A)
    const int jhi = tid >> 4;   // point slot 0..15

    __syncthreads();

    for (int c0 = blockIdx.x; c0 < chunks; c0 += gridDim.x) {
        const int cbase = c0 * 256;
        for (int b = 0; b < 16; ++b) {
            const int pbase = cbase + b * 16;
            // ---- phase A: fill E[16][KPAD] ----
            {
                const int p = pbase + jhi;
                const float x0 = X[p * 3 + 0];
                const float x1 = X[p * 3 + 1];
                const float x2 = X[p * 3 + 2];
#pragma unroll
                for (int u = 0; u < 6; ++u) {
                    const int k = f + 16 * u;
                    if (k < KPAD) {
                        float v = 0.f;
                        if (k < K) {
                            const float dx = x0 - qx0[k];
                            const float dy = x1 - qx1[k];
                            const float dz = x2 - qx2[k];
                            v = __expf((dx * dx + dy * dy + dz * dz) * invw2[k]);
                        }
                        E[jhi][k] = v;
                    }
                }
            }
            __syncthreads();
            // ---- phase B: accumulate ----
            const float Freg = F[(size_t)(pbase + jhi) * NFEAT + f];
#pragma unroll
            for (int k = 0; k < KPAD; k += 4) {
                const float4 ev = *reinterpret_cast<const float4*>(&E[jhi][k]);
                acc[k + 0] += ev.x * Freg;
                acc[k + 1] += ev.y * Freg;
                acc[k + 2] += ev.z * Freg;
                acc[k + 3] += ev.w * Freg;
            }
            __syncthreads();
        }
    }

    // ---- reduce acc over j ----
    // within wave: lanes differ in j by bits 4,5 of lane id
#pragma unroll
    for (int k = 0; k < KPAD; ++k) {
        float v = acc[k];
        v += __shfl_xor(v, 16);
        v += __shfl_xor(v, 32);
        acc[k] = v;
    }
    const int wv   = tid >> 6;
    const int lane = tid & 63;
    if (lane < 16) {
#pragma unroll
        for (int k = 0; k < KPAD; ++k) wred[wv][k][lane] = acc[k];
    }
    __syncthreads();
    const float* wr = &wred[0][0][0];
    for (int idx = tid; idx < KPAD * NFEAT; idx += 256) {
        const float s = wr[idx] + wr[KPAD * NFEAT + idx] +
                        wr[2 * KPAD * NFEAT + idx] + wr[3 * KPAD * NFEAT + idx];
        partial[(size_t)blockIdx.x * (KPAD * NFEAT) + idx] = s;
    }
}

// ---------------------------------------------------------------------------
// Kernel 1.5: fixed-order reduction of partials -> QF (applies omegaF).
// Grid = KPAD blocks (one per k), 256 threads = (f 0..15) x (g 0..15).
// ---------------------------------------------------------------------------
__global__ __launch_bounds__(256) void k1_reduce(
    const float* __restrict__ partial, const float* __restrict__ omegaF,
    int nb, float* __restrict__ QF)
{
    const int k   = blockIdx.x;
    const int tid = threadIdx.x;
    const int f = tid & 15, g = tid >> 4;
    float s = 0.f;
    for (int b = g; b < nb; b += 16)
        s += partial[(size_t)b * (KPAD * NFEAT) + k * NFEAT + f];
    __shared__ float red[16][17];
    red[g][f] = s;
    __syncthreads();
    if (tid < 16) {
        float t = 0.f;
#pragma unroll
        for (int g2 = 0; g2 < 16; ++g2) t += red[g2][tid];
        QF[k * NFEAT + tid] = t * omegaF[tid];
    }
}

// ---------------------------------------------------------------------------
// Kernel 2: per-point output row [F (16) | FxQFT (K) | FxQFT@QF (16)].
// One thread per point; single fused pass over k (QF row loaded once per k,
// uniform address -> scalar-cached).
// ---------------------------------------------------------------------------
__global__ __launch_bounds__(256) void k2_out(
    const float* __restrict__ F, const float* __restrict__ QF,
    int K, float* __restrict__ out)
{
    const int i = blockIdx.x * 256 + threadIdx.x;

    float fr[NFEAT];
    {
        const float4* Fv = reinterpret_cast<const float4*>(F + (size_t)i * NFEAT);
        const float4 t0 = Fv[0], t1 = Fv[1], t2 = Fv[2], t3 = Fv[3];
        fr[0]  = t0.x; fr[1]  = t0.y; fr[2]  = t0.z; fr[3]  = t0.w;
        fr[4]  = t1.x; fr[5]  = t1.y; fr[6]  = t1.z; fr[7]  = t1.w;
        fr[8]  = t2.x; fr[9]  = t2.y; fr[10] = t2.z; fr[11] = t2.w;
        fr[12] = t3.x; fr[13] = t3.y; fr[14] = t3.z; fr[15] = t3.w;
    }

    const size_t ob = (size_t)i * (NFEAT + 85 + NFEAT); // 117, K is always 85 here
    // section 1: copy F
#pragma unroll
    for (int f = 0; f < NFEAT; ++f) out[ob + f] = fr[f];

    float gacc[NFEAT];
#pragma unroll
    for (int f = 0; f < NFEAT; ++f) gacc[f] = 0.f;

    for (int k = 0; k < K; ++k) {
        const float4* qv = reinterpret_cast<const float4*>(QF + (size_t)k * NFEAT);
        const float4 q0 = qv[0], q1 = qv[1], q2 = qv[2], q3 = qv[3];
        float qr[NFEAT];
        qr[0]  = q0.x; qr[1]  = q0.y; qr[2]  = q0.z; qr[3]  = q0.w;
        qr[4]  = q1.x; qr[5]  = q1.y; qr[6]  = q1.z; qr[7]  = q1.w;
        qr[8]  = q2.x; qr[9]  = q2.y; qr[10] = q2.z; qr[11] = q2.w;
        qr[12] = q3.x; qr[13] = q3.y; qr[14] = q3.z; qr[15] = q3.w;

        float t = 0.f;
#pragma unroll
        for (int f = 0; f < NFEAT; ++f) t += fr[f] * qr[f];
        out[ob + NFEAT + k] = t;
#pragma unroll
        for (int f = 0; f < NFEAT; ++f) gacc[f] += t * qr[f];
    }

#pragma unroll
    for (int f = 0; f < NFEAT; ++f) out[ob + NFEAT + K + f] = gacc[f];
}

// ---------------------------------------------------------------------------
extern "C" void kernel_launch(void* const* d_in, const int* in_sizes, int n_in,
                              void* d_out, int out_size, void* d_ws, size_t ws_size,
                              hipStream_t stream)
{
    const float* X      = (const float*)d_in[0];
    const float* F      = (const float*)d_in[1];
    const float* QX     = (const float*)d_in[2];
    const float* omegaD = (const float*)d_in[3];
    const float* omegaF = (const float*)d_in[4];
    float* out = (float*)d_out;

    const int M = in_sizes[0] / 3;       // 262144
    const int K = in_sizes[3];           // 85
    const int chunks = M / 256;          // 1024

    // workspace layout: [nb][KPAD*16] partials, then [KPAD*16] QF
    const size_t per_block = (size_t)KPAD * NFEAT;
    int nb = (int)((ws_size / sizeof(float) - per_block) / per_block);
    if (nb > chunks) nb = chunks;
    if (nb > 1024) nb = 1024;
    if (nb < 1) nb = 1;

    float* partial = (float*)d_ws;
    float* QFbuf   = partial + (size_t)nb * per_block;

    hipLaunchKernelGGL(k1_partial, dim3(nb), dim3(256), 0, stream,
                       X, F, QX, omegaD, K, chunks, partial);
    hipLaunchKernelGGL(k1_reduce, dim3(KPAD), dim3(256), 0, stream,
                       partial, omegaF, nb, QFbuf);
    hipLaunchKernelGGL(k2_out, dim3(M / 256), dim3(256), 0, stream,
                       F, QFbuf, K, out);
}

// Round 2
// 105.815 us; speedup vs baseline: 1.7815x; 1.7815x over previous
//
#include <hip/hip_runtime.h>

#define KP    96      // K=85 padded to 96 (divisible into 24 quads)
#define NF    16
#define NCOL  117     // 16 + 85 + 16 output columns
#define EROW  128     // E row stride in floats (multiple of 32 banks)
#define PBLK  (KP * NF)   // 1536 floats per partial block

// ---------------------------------------------------------------------------
// Kernel 1: per-block partial QF accumulation.
// Per 16-point batch:
//   phase A (256 thr = 16 f x 16 j): E[j][k] = exp(d2 * invw2) into LDS
//     (XOR bank swizzle: quad (k>>2)^(j&7) within 128-float row)
//   phase B (192 thr = 12 kq x 2 fh x 8 jh): acc[8k][8f] register tile,
//     2 E-b128 + 2 F-b128 per j feed 64 FMAs.
// End: 3-round LDS reduce over jh, then partial[block] write.
// ---------------------------------------------------------------------------
__global__ __launch_bounds__(256) void k1_partial(
    const float* __restrict__ X, const float* __restrict__ F,
    const float* __restrict__ QX, const float* __restrict__ omegaD,
    int K, int chunks, float* __restrict__ partial)
{
    __shared__ float qx0[KP], qx1[KP], qx2[KP], invw2[KP];
    __shared__ __align__(16) float F_lds[16 * 20];     // rows padded to 20
    __shared__ __align__(16) float E[16 * EROW];       // 8 KB
    __shared__ __align__(16) float rscr[96][64];       // 24 KB reduce scratch

    const int tid = threadIdx.x;
    if (tid < KP) {
        float a = 0.f, b = 0.f, c = 0.f, iw = 0.f;
        if (tid < K) {
            a = QX[tid * 3 + 0];
            b = QX[tid * 3 + 1];
            c = QX[tid * 3 + 2];
            const float w = omegaD[tid];
            iw = 1.0f / (w * w);
        }
        qx0[tid] = a; qx1[tid] = b; qx2[tid] = c; invw2[tid] = iw;
    }

    // phase A roles
    const int f   = tid & 15;
    const int jhi = tid >> 4;
    // phase B roles (valid for tid < 192)
    const int kq = tid % 12;
    const int fh = (tid / 12) & 1;
    const int jh = tid / 24;

    float acc[8][8];
#pragma unroll
    for (int a2 = 0; a2 < 8; ++a2)
#pragma unroll
        for (int b2 = 0; b2 < 8; ++b2) acc[a2][b2] = 0.f;

    __syncthreads();

    for (int c0 = blockIdx.x; c0 < chunks; c0 += gridDim.x) {
        const int cbase = c0 * 256;
        for (int bt = 0; bt < 16; ++bt) {
            const int pbase = cbase + bt * 16;
            // ---- phase A ----
            {
                const int p = pbase + jhi;
                const float x0 = X[p * 3 + 0];
                const float x1 = X[p * 3 + 1];
                const float x2 = X[p * 3 + 2];
#pragma unroll
                for (int u = 0; u < 6; ++u) {
                    const int k = f + 16 * u;
                    float v = 0.f;
                    if (k < K) {
                        const float dx = x0 - qx0[k];
                        const float dy = x1 - qx1[k];
                        const float dz = x2 - qx2[k];
                        v = __expf((dx * dx + dy * dy + dz * dz) * invw2[k]);
                    }
                    E[EROW * jhi + 4 * ((k >> 2) ^ (jhi & 7)) + (k & 3)] = v;
                }
            }
            if (tid < 64) {
                const int j = tid >> 2, c4 = tid & 3;
                *reinterpret_cast<float4*>(&F_lds[j * 20 + 4 * c4]) =
                    *reinterpret_cast<const float4*>(&F[(size_t)(pbase + j) * NF + 4 * c4]);
            }
            __syncthreads();
            // ---- phase B ----
            if (tid < 192) {
#pragma unroll
                for (int jj = 0; jj < 2; ++jj) {
                    const int j  = jh + 8 * jj;
                    const int js = j & 7;   // == jh
                    const float4 ea = *reinterpret_cast<const float4*>(&E[EROW * j + 4 * (kq ^ js)]);
                    const float4 eb = *reinterpret_cast<const float4*>(&E[EROW * j + 4 * ((kq + 12) ^ js)]);
                    const float4 fa = *reinterpret_cast<const float4*>(&F_lds[j * 20 + 8 * fh]);
                    const float4 fb = *reinterpret_cast<const float4*>(&F_lds[j * 20 + 8 * fh + 4]);
                    const float e[8]  = {ea.x, ea.y, ea.z, ea.w, eb.x, eb.y, eb.z, eb.w};
                    const float fv[8] = {fa.x, fa.y, fa.z, fa.w, fb.x, fb.y, fb.z, fb.w};
#pragma unroll
                    for (int a2 = 0; a2 < 8; ++a2)
#pragma unroll
                        for (int b2 = 0; b2 < 8; ++b2)
                            acc[a2][b2] += e[a2] * fv[b2];
                }
            }
            __syncthreads();
        }
    }

    // ---- reduce over jh: 8 -> 4 -> 2 -> 1 ----
#define RSTORE(SLOT)                                                            \
    do {                                                                        \
        float* rp = rscr[SLOT];                                                 \
        _Pragma("unroll")                                                       \
        for (int a2 = 0; a2 < 8; ++a2) {                                        \
            *reinterpret_cast<float4*>(&rp[a2 * 8]) =                           \
                make_float4(acc[a2][0], acc[a2][1], acc[a2][2], acc[a2][3]);    \
            *reinterpret_cast<float4*>(&rp[a2 * 8 + 4]) =                       \
                make_float4(acc[a2][4], acc[a2][5], acc[a2][6], acc[a2][7]);    \
        }                                                                       \
    } while (0)
#define RADD(SLOT)                                                              \
    do {                                                                        \
        const float* rp = rscr[SLOT];                                           \
        _Pragma("unroll")                                                       \
        for (int a2 = 0; a2 < 8; ++a2) {                                        \
            const float4 r0 = *reinterpret_cast<const float4*>(&rp[a2 * 8]);    \
            const float4 r1 = *reinterpret_cast<const float4*>(&rp[a2 * 8 + 4]);\
            acc[a2][0] += r0.x; acc[a2][1] += r0.y;                             \
            acc[a2][2] += r0.z; acc[a2][3] += r0.w;                             \
            acc[a2][4] += r1.x; acc[a2][5] += r1.y;                             \
            acc[a2][6] += r1.z; acc[a2][7] += r1.w;                             \
        }                                                                       \
    } while (0)

    if (tid >= 96 && tid < 192) RSTORE(tid - 96);
    __syncthreads();
    if (tid < 96) RADD(tid);
    __syncthreads();
    if (tid >= 48 && tid < 96) RSTORE(tid - 48);
    __syncthreads();
    if (tid < 48) RADD(tid);
    __syncthreads();
    if (tid >= 24 && tid < 48) RSTORE(tid - 24);
    __syncthreads();
    if (tid < 24) {
        RADD(tid);
        float* pb = partial + (size_t)blockIdx.x * PBLK;
#pragma unroll
        for (int a2 = 0; a2 < 8; ++a2) {
            const int k = 4 * kq + (a2 & 3) + ((a2 >= 4) ? 48 : 0);
            *reinterpret_cast<float4*>(&pb[k * 16 + 8 * fh]) =
                make_float4(acc[a2][0], acc[a2][1], acc[a2][2], acc[a2][3]);
            *reinterpret_cast<float4*>(&pb[k * 16 + 8 * fh + 4]) =
                make_float4(acc[a2][4], acc[a2][5], acc[a2][6], acc[a2][7]);
        }
    }
}

// ---------------------------------------------------------------------------
// Kernel 1.5: fixed-order reduction of partials -> QF (applies omegaF).
// ---------------------------------------------------------------------------
__global__ __launch_bounds__(256) void k1_reduce(
    const float* __restrict__ partial, const float* __restrict__ omegaF,
    int nb, float* __restrict__ QF)
{
    const int k   = blockIdx.x;
    const int tid = threadIdx.x;
    const int f = tid & 15, g = tid >> 4;
    float s = 0.f;
    for (int b = g; b < nb; b += 16)
        s += partial[(size_t)b * PBLK + k * 16 + f];
    __shared__ float red[16][17];
    red[g][f] = s;
    __syncthreads();
    if (tid < 16) {
        float t = 0.f;
#pragma unroll
        for (int g2 = 0; g2 < 16; ++g2) t += red[g2][tid];
        QF[k * 16 + tid] = t * omegaF[tid];
    }
}

// ---------------------------------------------------------------------------
// Kernel 2: per-point rows [F | FxQFT | FxQFT@QF], LDS-staged + coalesced
// float4 flush. 256 thr = 8 k-lanes x 32 point-pairs; 4 sub-batches of 64
// points per block. QF in LDS padded to 20 floats/row -> the 8 k-lanes hit
// 8 disjoint bank-quads (stride 5 quads, gcd(5,8)=1): conflict-free b128.
// ---------------------------------------------------------------------------
__global__ __launch_bounds__(256) void k2_out(
    const float* __restrict__ F, const float* __restrict__ QFb,
    float* __restrict__ out)
{
    __shared__ __align__(16) float QF_lds[85 * 20];
    __shared__ __align__(16) float row[64 * NCOL];   // 29,952 B

    const int tid = threadIdx.x;
    for (int idx = tid; idx < 85 * 16; idx += 256) {
        const int k = idx >> 4, f2 = idx & 15;
        QF_lds[k * 20 + f2] = QFb[idx];
    }
    __syncthreads();

    const int q  = tid & 7;    // k-lane
    const int pp = tid >> 3;   // point-pair 0..31
    const int cbase = blockIdx.x * 256;

    for (int sb = 0; sb < 4; ++sb) {
        const int base = cbase + sb * 64;
        const int i0 = base + pp;
        const int i1 = i0 + 32;

        float fr0[NF], fr1[NF];
        {
            const float4* Fv0 = reinterpret_cast<const float4*>(F + (size_t)i0 * NF);
            const float4* Fv1 = reinterpret_cast<const float4*>(F + (size_t)i1 * NF);
#pragma unroll
            for (int u = 0; u < 4; ++u) {
                const float4 t0 = Fv0[u], t1 = Fv1[u];
                fr0[4 * u + 0] = t0.x; fr0[4 * u + 1] = t0.y;
                fr0[4 * u + 2] = t0.z; fr0[4 * u + 3] = t0.w;
                fr1[4 * u + 0] = t1.x; fr1[4 * u + 1] = t1.y;
                fr1[4 * u + 2] = t1.z; fr1[4 * u + 3] = t1.w;
            }
        }
        // F section (each k-lane writes its 2-float slice)
        row[pp * NCOL + 2 * q]            = fr0[2 * q];
        row[pp * NCOL + 2 * q + 1]        = fr0[2 * q + 1];
        row[(pp + 32) * NCOL + 2 * q]     = fr1[2 * q];
        row[(pp + 32) * NCOL + 2 * q + 1] = fr1[2 * q + 1];

        float g0[NF], g1[NF];
#pragma unroll
        for (int u = 0; u < NF; ++u) { g0[u] = 0.f; g1[u] = 0.f; }

        for (int k = q; k < 85; k += 8) {
            const float* qp = &QF_lds[k * 20];
            const float4 q0 = *reinterpret_cast<const float4*>(qp);
            const float4 q1 = *reinterpret_cast<const float4*>(qp + 4);
            const float4 q2 = *reinterpret_cast<const float4*>(qp + 8);
            const float4 q3 = *reinterpret_cast<const float4*>(qp + 12);
            float qr[NF];
            qr[0]  = q0.x; qr[1]  = q0.y; qr[2]  = q0.z; qr[3]  = q0.w;
            qr[4]  = q1.x; qr[5]  = q1.y; qr[6]  = q1.z; qr[7]  = q1.w;
            qr[8]  = q2.x; qr[9]  = q2.y; qr[10] = q2.z; qr[11] = q2.w;
            qr[12] = q3.x; qr[13] = q3.y; qr[14] = q3.z; qr[15] = q3.w;

            float t0 = 0.f, t1 = 0.f;
#pragma unroll
            for (int u = 0; u < NF; ++u) { t0 += fr0[u] * qr[u]; t1 += fr1[u] * qr[u]; }
            row[pp * NCOL + 16 + k]        = t0;
            row[(pp + 32) * NCOL + 16 + k] = t1;
#pragma unroll
            for (int u = 0; u < NF; ++u) { g0[u] += t0 * qr[u]; g1[u] += t1 * qr[u]; }
        }

        // reduce g over the 8 k-lanes (lane bits 0..2)
#pragma unroll
        for (int m = 1; m <= 4; m <<= 1) {
#pragma unroll
            for (int u = 0; u < NF; ++u) {
                g0[u] += __shfl_xor(g0[u], m);
                g1[u] += __shfl_xor(g1[u], m);
            }
        }
        row[pp * NCOL + 101 + 2 * q]            = g0[2 * q];
        row[pp * NCOL + 101 + 2 * q + 1]        = g0[2 * q + 1];
        row[(pp + 32) * NCOL + 101 + 2 * q]     = g1[2 * q];
        row[(pp + 32) * NCOL + 101 + 2 * q + 1] = g1[2 * q + 1];

        __syncthreads();
        // coalesced flush: 64 rows x 117 floats = 1872 float4
        {
            float4* dst = reinterpret_cast<float4*>(out + (size_t)base * NCOL);
            const float4* src = reinterpret_cast<const float4*>(row);
            for (int t = tid; t < (64 * NCOL) / 4; t += 256) dst[t] = src[t];
        }
        __syncthreads();
    }
}

// ---------------------------------------------------------------------------
extern "C" void kernel_launch(void* const* d_in, const int* in_sizes, int n_in,
                              void* d_out, int out_size, void* d_ws, size_t ws_size,
                              hipStream_t stream)
{
    const float* X      = (const float*)d_in[0];
    const float* F      = (const float*)d_in[1];
    const float* QX     = (const float*)d_in[2];
    const float* omegaD = (const float*)d_in[3];
    const float* omegaF = (const float*)d_in[4];
    float* out = (float*)d_out;

    const int M = in_sizes[0] / 3;       // 262144
    const int K = in_sizes[3];           // 85
    const int chunks = M / 256;          // 1024

    int nb = (int)((ws_size / sizeof(float) - PBLK) / PBLK);
    if (nb > chunks) nb = chunks;
    if (nb > 1024) nb = 1024;
    if (nb < 1) nb = 1;

    float* partial = (float*)d_ws;
    float* QFbuf   = partial + (size_t)nb * PBLK;

    hipLaunchKernelGGL(k1_partial, dim3(nb), dim3(256), 0, stream,
                       X, F, QX, omegaD, K, chunks, partial);
    hipLaunchKernelGGL(k1_reduce, dim3(KP), dim3(256), 0, stream,
                       partial, omegaF, nb, QFbuf);
    hipLaunchKernelGGL(k2_out, dim3(M / 256), dim3(256), 0, stream,
                       F, QFbuf, out);
}